// Round 1
// baseline (80.087 us; speedup 1.0000x reference)
//
#include <hip/hip_runtime.h>
#include <math.h>

#define NROWS 262144
#define DDIM  128
#define GRID_BLOCKS 2048

// online logsumexp merge: (m,s) <- merge((m,s),(m2,s2))
// identity element: m = -3e38f, s = 0 (no NaN: -3e38 - -3e38 = 0, exp(0)*0 = 0)
__device__ inline void lse_merge(float& m, float& s, float m2, float s2) {
    float mm = fmaxf(m, m2);
    s = s * expf(m - mm) + s2 * expf(m2 - mm);
    m = mm;
}

__global__ __launch_bounds__(256) void angular_partial_kernel(
    const float* __restrict__ A, const float* __restrict__ P,
    const float* __restrict__ Ng, const int* __restrict__ alpha,
    float2* __restrict__ partials)
{
    // t2 = tan(pi*alpha/180)^2 computed in double (matches np double constant)
    double ar = M_PI * (double)alpha[0] / 180.0;
    double td = tan(ar);
    float c1 = (float)(4.0 * td * td);          //  4*t2
    float c2 = (float)(2.0 * (1.0 + td * td));  //  2*(1+t2)

    const int tid  = threadIdx.x;
    const int lane = tid & 63;
    const int waveInBlock = tid >> 6;   // 0..3
    const int half = lane >> 5;         // which row of the pair
    const int c4   = lane & 31;         // float4 column within row (D=128 -> 32 float4)

    const float4* A4 = (const float4*)A;
    const float4* P4 = (const float4*)P;
    const float4* N4 = (const float4*)Ng;

    float m = -3.0e38f, s = 0.0f;

    const int wavesPerGrid = gridDim.x * 4;
    const int waveId = blockIdx.x * 4 + waveInBlock;

    // each wave handles 2 adjacent rows per iteration (1 KiB contiguous per load inst)
    for (int rp = waveId; rp < NROWS / 2; rp += wavesPerGrid) {
        int row = rp * 2 + half;
        int idx = row * 32 + c4;
        float4 av = A4[idx];
        float4 pv = P4[idx];
        float4 nv = N4[idx];

        float ap  = av.x * pv.x + av.y * pv.y + av.z * pv.z + av.w * pv.w;
        float apn = (av.x + pv.x) * nv.x + (av.y + pv.y) * nv.y
                  + (av.z + pv.z) * nv.z + (av.w + pv.w) * nv.w;

        // segmented butterfly reduce over the 32-lane row group
        #pragma unroll
        for (int off = 16; off; off >>= 1) {
            ap  += __shfl_xor(ap,  off, 32);
            apn += __shfl_xor(apn, off, 32);
        }

        if (c4 == 0) {
            float f = c1 * apn - c2 * ap;
            float mm = fmaxf(m, f);
            s = s * expf(m - mm) + expf(f - mm);
            m = mm;
        }
    }

    // wave-level merge across all 64 lanes (non-contributing lanes hold identity)
    #pragma unroll
    for (int off = 32; off; off >>= 1) {
        float m2 = __shfl_xor(m, off, 64);
        float s2 = __shfl_xor(s, off, 64);
        lse_merge(m, s, m2, s2);
    }

    __shared__ float sm[4];
    __shared__ float ss[4];
    if (lane == 0) { sm[waveInBlock] = m; ss[waveInBlock] = s; }
    __syncthreads();

    if (tid == 0) {
        float M = sm[0], S = ss[0];
        #pragma unroll
        for (int w = 1; w < 4; w++) lse_merge(M, S, sm[w], ss[w]);
        partials[blockIdx.x] = make_float2(M, S);
    }
}

__global__ __launch_bounds__(256) void angular_finalize_kernel(
    const float2* __restrict__ partials, int nPart, float* __restrict__ out)
{
    const int tid  = threadIdx.x;
    const int lane = tid & 63;
    const int waveInBlock = tid >> 6;

    float m = -3.0e38f, s = 0.0f;
    for (int i = tid; i < nPart; i += 256) {
        float2 p = partials[i];
        lse_merge(m, s, p.x, p.y);
    }

    #pragma unroll
    for (int off = 32; off; off >>= 1) {
        float m2 = __shfl_xor(m, off, 64);
        float s2 = __shfl_xor(s, off, 64);
        lse_merge(m, s, m2, s2);
    }

    __shared__ float sm[4];
    __shared__ float ss[4];
    if (lane == 0) { sm[waveInBlock] = m; ss[waveInBlock] = s; }
    __syncthreads();

    if (tid == 0) {
        float M = sm[0], S = ss[0];
        #pragma unroll
        for (int w = 1; w < 4; w++) lse_merge(M, S, sm[w], ss[w]);
        out[0] = M + logf(S);
    }
}

extern "C" void kernel_launch(void* const* d_in, const int* in_sizes, int n_in,
                              void* d_out, int out_size, void* d_ws, size_t ws_size,
                              hipStream_t stream) {
    const float* A  = (const float*)d_in[0];
    const float* P  = (const float*)d_in[1];
    const float* Ng = (const float*)d_in[2];
    const int* alpha = (const int*)d_in[3];
    float* out = (float*)d_out;
    float2* partials = (float2*)d_ws;

    angular_partial_kernel<<<GRID_BLOCKS, 256, 0, stream>>>(A, P, Ng, alpha, partials);
    angular_finalize_kernel<<<1, 256, 0, stream>>>(partials, GRID_BLOCKS, out);
}